// Round 8
// baseline (450.654 us; speedup 1.0000x reference)
//
#include <hip/hip_runtime.h>
#include <math.h>

#define N_NODES 50000
#define N_GRAPHS 64
#define HID 128
#define SCAN_B 196   // ceil(50000/256)
#define NODE_BLKS 196
#define NBUCK 128
#define AP 132       // padded LDS row stride (halfs) for epilogue A-tile

typedef _Float16 half8 __attribute__((ext_vector_type(8)));
typedef float f32x4 __attribute__((ext_vector_type(4)));
typedef int i32x4 __attribute__((ext_vector_type(4)));

__device__ __forceinline__ float lrelu(float e) { return e > 0.f ? e : 0.2f * e; }
__device__ __forceinline__ float elu_fast(float o) { return o > 0.f ? o : __expf(o) - 1.f; }

// acc += f16(lo/hi half of h2) * c, product+accumulate in f32 — one VALU op
__device__ __forceinline__ void fmix_lo(float& a, int h2, float c) {
    asm("v_fma_mix_f32 %0, %1, %2, %0 op_sel_hi:[1,0,0]" : "+v"(a) : "v"(h2), "v"(c));
}
__device__ __forceinline__ void fmix_hi(float& a, int h2, float c) {
    asm("v_fma_mix_f32 %0, %1, %2, %0 op_sel:[1,0,0] op_sel_hi:[1,0,0]" : "+v"(a) : "v"(h2), "v"(c));
}

__device__ __forceinline__ int estart(const int* __restrict__ start, int g) {
    for (; g < N_GRAPHS; ++g) {
        int v = start[g];
        if (v >= 0) return v;
    }
    return N_NODES;
}

// ---------------- CSR count (+ per-edge rank epos) + fused weight prep ----------------
__global__ void count_prep(const int* __restrict__ dst, int n_e, int nblk,
                           int* __restrict__ counts, int* __restrict__ epos,
                           int* __restrict__ start,
                           int* __restrict__ dhist, int* __restrict__ gcur,
                           const float* __restrict__ W0, const float* __restrict__ W1,
                           const float* __restrict__ W2,
                           const float* __restrict__ as0, const float* __restrict__ ad0,
                           const float* __restrict__ as1, const float* __restrict__ ad1,
                           const float* __restrict__ as2, const float* __restrict__ ad2,
                           _Float16* __restrict__ Wh0, _Float16* __restrict__ Wh1,
                           _Float16* __restrict__ Wh2,
                           float* __restrict__ wfold) {
    int blk = blockIdx.x;
    if (blk < nblk) {
        if (blk == 0) {
            if (threadIdx.x <= N_GRAPHS) start[threadIdx.x] = -1;
            if (threadIdx.x < NBUCK) { dhist[threadIdx.x] = 0; gcur[threadIdx.x] = 0; }
        }
        int e = blk * 256 + threadIdx.x;
        if (e < n_e) epos[e] = atomicAdd(&counts[dst[e]], 1);  // rank within dst segment
        return;
    }
    int b = blk - nblk;  // 0..29
    if (b < 24) {
        int layer = b >> 3;
        const float* W = layer == 0 ? W0 : (layer == 1 ? W1 : W2);
        _Float16* Wh = layer == 0 ? Wh0 : (layer == 1 ? Wh1 : Wh2);
        int t = (b & 7) * 256 + threadIdx.x;
        int lane = t & 63;
        int nt = (t >> 6) & 7;
        int kt = t >> 9;
        int n = nt * 16 + (lane & 15);
        int kbase = kt * 32 + (lane >> 4) * 8;
#pragma unroll
        for (int j = 0; j < 8; ++j) {
            float w = W[(size_t)(kbase + j) * 128 + n];
            Wh[(size_t)t * 8 + j] = (_Float16)w;
        }
    } else {
        int idx = b - 24;  // 0..5: layer*2 + which
        int layer = idx >> 1, which = idx & 1;
        const float* W = layer == 0 ? W0 : (layer == 1 ? W1 : W2);
        const float* a = which == 0 ? (layer == 0 ? as0 : (layer == 1 ? as1 : as2))
                                    : (layer == 0 ? ad0 : (layer == 1 ? ad1 : ad2));
        int k = threadIdx.x;
        if (k < 128) {
            float s = 0.f;
            for (int j = 0; j < 128; ++j) s = fmaf(W[k * 128 + j], a[j], s);
            wfold[idx * 128 + k] = s;
        }
    }
}

__global__ __launch_bounds__(256) void block_reduce(const int* __restrict__ counts,
                                                    int* __restrict__ bsum) {
    __shared__ int red[256];
    int t = threadIdx.x;
    int i = blockIdx.x * 256 + t;
    red[t] = (i < N_NODES) ? counts[i] : 0;
    __syncthreads();
#pragma unroll
    for (int off = 128; off; off >>= 1) {
        if (t < off) red[t] += red[t + off];
        __syncthreads();
    }
    if (t == 0) bsum[blockIdx.x] = red[0];
}

// fused: per-block redundant scan of bsum + local scan + boundary detection + degree histogram
__global__ __launch_bounds__(256) void block_scan(const int* __restrict__ counts,
                                                  const int* __restrict__ bsum,
                                                  const int* __restrict__ batch,
                                                  int* __restrict__ offs,
                                                  int* __restrict__ start,
                                                  int* __restrict__ dhist) {
    __shared__ int sb[256];
    __shared__ int sh[256];
    __shared__ int lh[NBUCK];
    int t = threadIdx.x;
    if (t < NBUCK) lh[t] = 0;
    int v = (t < SCAN_B) ? bsum[t] : 0;
    sb[t] = v;
    __syncthreads();
#pragma unroll
    for (int off = 1; off < 256; off <<= 1) {
        int u = (t >= off) ? sb[t - off] : 0;
        __syncthreads();
        sb[t] += u;
        __syncthreads();
    }
    int bpre = (blockIdx.x == 0) ? 0 : sb[blockIdx.x - 1];
    if (blockIdx.x == 0 && t == SCAN_B - 1) offs[N_NODES] = sb[t];

    int i = blockIdx.x * 256 + t;
    int c = (i < N_NODES) ? counts[i] : 0;
    sh[t] = c;
    __syncthreads();
#pragma unroll
    for (int off = 1; off < 256; off <<= 1) {
        int u = (t >= off) ? sh[t - off] : 0;
        __syncthreads();
        sh[t] += u;
        __syncthreads();
    }
    if (i < N_NODES) {
        int e = bpre + sh[t] - c;
        offs[i] = e;
        int b = batch[i];
        if (i == 0) start[b] = 0;
        else if (batch[i - 1] != b) start[b] = i;
        atomicAdd(&lh[c < NBUCK - 1 ? c : NBUCK - 1], 1);
    }
    __syncthreads();
    if (t < NBUCK) {
        int n = lh[t];
        if (n) atomicAdd(&dhist[t], n);
    }
}

// edge scatter (ATOMIC-FREE via epos) + d_out zeroing + degree-bucket placement
__global__ __launch_bounds__(256) void scatter_kernel(const int* __restrict__ src,
                                                      const int* __restrict__ dst, int n_e,
                                                      const int* __restrict__ epos,
                                                      int* __restrict__ csr_src,
                                                      float* __restrict__ outz,
                                                      const int* __restrict__ offs,
                                                      const int* __restrict__ dhist,
                                                      int* __restrict__ gcur,
                                                      int* __restrict__ order) {
    int gid = blockIdx.x * 256 + threadIdx.x;
    if (gid < N_GRAPHS * HID) outz[gid] = 0.f;
    if (gid < n_e) {
        int d = dst[gid];
        csr_src[offs[d] + epos[gid]] = src[gid];
    }
    if (blockIdx.x >= NODE_BLKS) return;

    // two-level counting placement: block-local hist -> one global atomic per bucket
    __shared__ int lh[NBUCK], sc[NBUCK], lbase[NBUCK];
    int t = threadIdx.x;
    if (t < NBUCK) lh[t] = 0;
    __syncthreads();
    int b = -1, lpos = 0;
    if (gid < N_NODES) {
        int deg = offs[gid + 1] - offs[gid];
        b = deg < NBUCK - 1 ? deg : NBUCK - 1;
        lpos = atomicAdd(&lh[b], 1);
    }
    __syncthreads();
    if (t < NBUCK) sc[t] = dhist[t];
    __syncthreads();
    for (int off = 1; off < NBUCK; off <<= 1) {
        int u = (t < NBUCK && t >= off) ? sc[t - off] : 0;
        __syncthreads();
        if (t < NBUCK) sc[t] += u;
        __syncthreads();
    }
    if (t < NBUCK) {
        int excl = t ? sc[t - 1] : 0;
        int cnt = lh[t];
        int bb = cnt ? atomicAdd(&gcur[t], cnt) : 0;
        lbase[t] = excl + bb;
    }
    __syncthreads();
    if (gid < N_NODES) order[lbase[b] + lpos] = gid;
}

// ---------------- MFMA GEMM (layer 1): H16 = fp16(X)@fp16(W); exact fp32 alphas ----------------
__global__ __launch_bounds__(256) void gemm_mfma(const float* __restrict__ X,
                                                 const _Float16* __restrict__ Wh,
                                                 const float* __restrict__ wsv,
                                                 const float* __restrict__ wdv,
                                                 _Float16* __restrict__ H16,
                                                 float* __restrict__ AS,
                                                 float* __restrict__ AD) {
    __shared__ float wsL[128], wdL[128];
    int t = threadIdx.x;
    if (t < 128) wsL[t] = wsv[t];
    else if (t < 256) wdL[t - 128] = wdv[t - 128];
    __syncthreads();

    int wave = t >> 6, lane = t & 63;
    int m15 = lane & 15, quad = lane >> 4;
    int rowbase = blockIdx.x * 64 + wave * 16;
    int arow = rowbase + m15;
    bool arow_ok = arow < N_NODES;

    f32x4 acc[8];
#pragma unroll
    for (int nt = 0; nt < 8; ++nt) acc[nt] = (f32x4){0.f, 0.f, 0.f, 0.f};
    float as_p = 0.f, ad_p = 0.f;

    const float* xrow = X + (size_t)arow * 128 + quad * 8;
#pragma unroll
    for (int kt = 0; kt < 4; ++kt) {
        f32x4 a0 = (f32x4){0.f, 0.f, 0.f, 0.f};
        f32x4 a1 = (f32x4){0.f, 0.f, 0.f, 0.f};
        if (arow_ok) {
            a0 = *(const f32x4*)(xrow + kt * 32);
            a1 = *(const f32x4*)(xrow + kt * 32 + 4);
        }
        int kb = kt * 32 + quad * 8;
        half8 ah;
#pragma unroll
        for (int j = 0; j < 4; ++j) {
            as_p = fmaf(a0[j], wsL[kb + j], as_p);
            ad_p = fmaf(a0[j], wdL[kb + j], ad_p);
            as_p = fmaf(a1[j], wsL[kb + 4 + j], as_p);
            ad_p = fmaf(a1[j], wdL[kb + 4 + j], ad_p);
            ah[j] = (_Float16)a0[j];
            ah[4 + j] = (_Float16)a1[j];
        }
#pragma unroll
        for (int nt = 0; nt < 8; ++nt) {
            size_t fidx = ((size_t)((kt * 8 + nt) * 64 + lane)) * 8;
            half8 bh = *(const half8*)(Wh + fidx);
            acc[nt] = __builtin_amdgcn_mfma_f32_16x16x32_f16(ah, bh, acc[nt], 0, 0, 0);
        }
    }

#pragma unroll
    for (int nt = 0; nt < 8; ++nt) {
        int c = nt * 16 + m15;
#pragma unroll
        for (int reg = 0; reg < 4; ++reg) {
            int gr = rowbase + quad * 4 + reg;
            if (gr < N_NODES) H16[(size_t)gr * 128 + c] = (_Float16)acc[nt][reg];
        }
    }
    as_p += __shfl_xor(as_p, 16);
    ad_p += __shfl_xor(ad_p, 16);
    as_p += __shfl_xor(as_p, 32);
    ad_p += __shfl_xor(ad_p, 32);
    if (quad == 0 && arow_ok) { AS[arow] = as_p; AD[arow] = ad_p; }
}

// ---------------- fused softmax + fp16 gather + epilogue ----------------
// Layers 1/2: next-layer GEMM epilogue (Whn != null). Layer 3: fused global_mean_pool —
// pre-divided atomicAdd into POOL (d_out), no FA materialization, no pool dispatch.
__global__ __launch_bounds__(256) void aggregate_kernel(const _Float16* __restrict__ H16,
                                                        const float* __restrict__ AS,
                                                        const float* __restrict__ AD,
                                                        const int* __restrict__ offs,
                                                        const int* __restrict__ csr_src,
                                                        const int* __restrict__ order,
                                                        const float* __restrict__ bias,
                                                        const _Float16* __restrict__ Whn,
                                                        const float* __restrict__ wfn,
                                                        _Float16* __restrict__ Hn,
                                                        float* __restrict__ ASn,
                                                        float* __restrict__ ADn,
                                                        const int* __restrict__ batch,
                                                        const int* __restrict__ start,
                                                        float* __restrict__ POOL) {
    __shared__ int2 sh_sp[16][64];
    __shared__ _Float16 aW[16][AP];
    __shared__ int nds[16];
    int tid = threadIdx.x;
    int quad = tid >> 4;
    int l16 = tid & 15;
    int node = order[blockIdx.x * 16 + quad];

    int beg = offs[node];
    int deg = offs[node + 1] - beg;
    float ad = AD[node];
    float eself = lrelu(AS[node] + ad);
    const i32x4* H4 = (const i32x4*)H16;
    i32x4 hsv = H4[(size_t)node * 16 + l16];
    bool fast = deg <= 64;

    float m, ssum = 0.f, ps;
    if (fast) {
        float mym = -INFINITY;
        for (int i = l16; i < deg; i += 16) {
            int sv = csr_src[beg + i];
            float e = lrelu(AS[sv] + ad);
            sh_sp[quad][i] = make_int2(sv, __float_as_int(e));
            mym = fmaxf(mym, e);
        }
#pragma unroll
        for (int off = 8; off; off >>= 1) mym = fmaxf(mym, __shfl_xor(mym, off, 16));
        m = fmaxf(mym, eself);
        ps = __expf(eself - m);
        for (int i = l16; i < deg; i += 16) {
            int2 sp = sh_sp[quad][i];
            float p = __expf(__int_as_float(sp.y) - m);
            sh_sp[quad][i] = make_int2(sp.x, __float_as_int(p));
            ssum += p;
        }
    } else {
        float mym = -INFINITY;
        for (int i = beg + l16; i < beg + deg; i += 16)
            mym = fmaxf(mym, lrelu(AS[csr_src[i]] + ad));
#pragma unroll
        for (int off = 8; off; off >>= 1) mym = fmaxf(mym, __shfl_xor(mym, off, 16));
        m = fmaxf(mym, eself);
        ps = __expf(eself - m);
        for (int i = beg + l16; i < beg + deg; i += 16)
            ssum += __expf(lrelu(AS[csr_src[i]] + ad) - m);
    }

    float accA[8] = {0.f, 0.f, 0.f, 0.f, 0.f, 0.f, 0.f, 0.f};
    float accB[8] = {0.f, 0.f, 0.f, 0.f, 0.f, 0.f, 0.f, 0.f};

    if (fast) {
        int k = 0;
        for (; k + 3 < deg; k += 4) {
            int2 sp0 = sh_sp[quad][k];
            int2 sp1 = sh_sp[quad][k + 1];
            int2 sp2 = sh_sp[quad][k + 2];
            int2 sp3 = sh_sp[quad][k + 3];
            i32x4 h0 = H4[(size_t)sp0.x * 16 + l16];
            i32x4 h1 = H4[(size_t)sp1.x * 16 + l16];
            i32x4 h2 = H4[(size_t)sp2.x * 16 + l16];
            i32x4 h3 = H4[(size_t)sp3.x * 16 + l16];
            float c0 = __int_as_float(sp0.y), c1 = __int_as_float(sp1.y);
            float c2 = __int_as_float(sp2.y), c3 = __int_as_float(sp3.y);
#pragma unroll
            for (int j = 0; j < 4; ++j) {
                fmix_lo(accA[2 * j], h0[j], c0);
                fmix_hi(accA[2 * j + 1], h0[j], c0);
                fmix_lo(accB[2 * j], h1[j], c1);
                fmix_hi(accB[2 * j + 1], h1[j], c1);
            }
#pragma unroll
            for (int j = 0; j < 4; ++j) {
                fmix_lo(accA[2 * j], h2[j], c2);
                fmix_hi(accA[2 * j + 1], h2[j], c2);
                fmix_lo(accB[2 * j], h3[j], c3);
                fmix_hi(accB[2 * j + 1], h3[j], c3);
            }
        }
        for (; k < deg; ++k) {
            int2 sp0 = sh_sp[quad][k];
            float c0 = __int_as_float(sp0.y);
            i32x4 h0 = H4[(size_t)sp0.x * 16 + l16];
#pragma unroll
            for (int j = 0; j < 4; ++j) {
                fmix_lo(accA[2 * j], h0[j], c0);
                fmix_hi(accA[2 * j + 1], h0[j], c0);
            }
        }
    } else {
        for (int k = 0; k < deg; ++k) {
            int s = csr_src[beg + k];
            float c = __expf(lrelu(AS[s] + ad) - m);
            i32x4 h0 = H4[(size_t)s * 16 + l16];
#pragma unroll
            for (int j = 0; j < 4; ++j) {
                fmix_lo(accA[2 * j], h0[j], c);
                fmix_hi(accA[2 * j + 1], h0[j], c);
            }
        }
    }

#pragma unroll
    for (int j = 0; j < 4; ++j) {
        fmix_lo(accA[2 * j], hsv[j], ps);
        fmix_hi(accA[2 * j + 1], hsv[j], ps);
    }
#pragma unroll
    for (int off = 8; off; off >>= 1) ssum += __shfl_xor(ssum, off, 16);
    float inv = __builtin_amdgcn_rcpf(ssum + ps + 1e-16f);

    int c0i = l16 * 8;
    f32x4 b0 = ((const f32x4*)bias)[l16 * 2];
    f32x4 b1 = ((const f32x4*)bias)[l16 * 2 + 1];
    f32x4 o0, o1;
    o0.x = elu_fast(fmaf(accA[0] + accB[0], inv, b0.x));
    o0.y = elu_fast(fmaf(accA[1] + accB[1], inv, b0.y));
    o0.z = elu_fast(fmaf(accA[2] + accB[2], inv, b0.z));
    o0.w = elu_fast(fmaf(accA[3] + accB[3], inv, b0.w));
    o1.x = elu_fast(fmaf(accA[4] + accB[4], inv, b1.x));
    o1.y = elu_fast(fmaf(accA[5] + accB[5], inv, b1.y));
    o1.z = elu_fast(fmaf(accA[6] + accB[6], inv, b1.z));
    o1.w = elu_fast(fmaf(accA[7] + accB[7], inv, b1.w));

    if (POOL) {
        // fused global_mean_pool: pre-divided atomic accumulate into d_out
        int g = batch[node];
        int s0 = estart(start, g), e1 = estart(start, g + 1);
        int cnt = e1 - s0;
        float r = 1.f / (float)(cnt > 1 ? cnt : 1);
        float* dst = POOL + (size_t)g * 128 + c0i;
        atomicAdd(&dst[0], o0.x * r);
        atomicAdd(&dst[1], o0.y * r);
        atomicAdd(&dst[2], o0.z * r);
        atomicAdd(&dst[3], o0.w * r);
        atomicAdd(&dst[4], o1.x * r);
        atomicAdd(&dst[5], o1.y * r);
        atomicAdd(&dst[6], o1.z * r);
        atomicAdd(&dst[7], o1.w * r);
    }

    if (Whn) {
        const float* wsn = wfn;
        const float* wdn = wfn + 128;
        float asn = o0.x * wsn[c0i] + o0.y * wsn[c0i + 1] + o0.z * wsn[c0i + 2] +
                    o0.w * wsn[c0i + 3] + o1.x * wsn[c0i + 4] + o1.y * wsn[c0i + 5] +
                    o1.z * wsn[c0i + 6] + o1.w * wsn[c0i + 7];
        float adn = o0.x * wdn[c0i] + o0.y * wdn[c0i + 1] + o0.z * wdn[c0i + 2] +
                    o0.w * wdn[c0i + 3] + o1.x * wdn[c0i + 4] + o1.y * wdn[c0i + 5] +
                    o1.z * wdn[c0i + 6] + o1.w * wdn[c0i + 7];
#pragma unroll
        for (int off = 8; off; off >>= 1) {
            asn += __shfl_xor(asn, off, 16);
            adn += __shfl_xor(adn, off, 16);
        }
        if (l16 == 0) {
            ASn[node] = asn;
            ADn[node] = adn;
            nds[quad] = node;
        }
        half8 hh;
        hh[0] = (_Float16)o0.x; hh[1] = (_Float16)o0.y;
        hh[2] = (_Float16)o0.z; hh[3] = (_Float16)o0.w;
        hh[4] = (_Float16)o1.x; hh[5] = (_Float16)o1.y;
        hh[6] = (_Float16)o1.z; hh[7] = (_Float16)o1.w;
        *(half8*)&aW[quad][c0i] = hh;
        __syncthreads();

        int wv = tid >> 6, lane = tid & 63;
        int m15 = lane & 15, eq = lane >> 4;
        f32x4 acc0 = (f32x4){0.f, 0.f, 0.f, 0.f};
        f32x4 acc1 = (f32x4){0.f, 0.f, 0.f, 0.f};
#pragma unroll
        for (int kt = 0; kt < 4; ++kt) {
            half8 ah = *(const half8*)&aW[m15][kt * 32 + eq * 8];
            half8 bh0 = *(const half8*)(Whn + ((size_t)((kt * 8 + wv * 2) * 64 + lane)) * 8);
            half8 bh1 = *(const half8*)(Whn + ((size_t)((kt * 8 + wv * 2 + 1) * 64 + lane)) * 8);
            acc0 = __builtin_amdgcn_mfma_f32_16x16x32_f16(ah, bh0, acc0, 0, 0, 0);
            acc1 = __builtin_amdgcn_mfma_f32_16x16x32_f16(ah, bh1, acc1, 0, 0, 0);
        }
#pragma unroll
        for (int reg = 0; reg < 4; ++reg) {
            int nid = nds[eq * 4 + reg];
            Hn[(size_t)nid * 128 + wv * 32 + m15] = (_Float16)acc0[reg];
            Hn[(size_t)nid * 128 + wv * 32 + 16 + m15] = (_Float16)acc1[reg];
        }
    }
}

extern "C" void kernel_launch(void* const* d_in, const int* in_sizes, int n_in,
                              void* d_out, int out_size, void* d_ws, size_t ws_size,
                              hipStream_t stream) {
    const float* x = (const float*)d_in[0];
    const int* edge_index = (const int*)d_in[1];
    const int* batch = (const int*)d_in[2];
    const float* W[3]   = {(const float*)d_in[3], (const float*)d_in[7], (const float*)d_in[11]};
    const float* avs[3] = {(const float*)d_in[4], (const float*)d_in[8], (const float*)d_in[12]};
    const float* avd[3] = {(const float*)d_in[5], (const float*)d_in[9], (const float*)d_in[13]};
    const float* bb[3]  = {(const float*)d_in[6], (const float*)d_in[10], (const float*)d_in[14]};
    int E0 = in_sizes[1] / 2;
    const int* esrc = edge_index;
    const int* edst = edge_index + E0;

    char* p = (char*)d_ws;
    auto alloc = [&](size_t bytes) -> void* {
        void* q = (void*)p;
        p += (bytes + 255) & ~(size_t)255;
        return q;
    };
    int* counts   = (int*)alloc((size_t)N_NODES * 4);
    int* offs     = (int*)alloc((size_t)(N_NODES + 1) * 4);
    int* epos     = (int*)alloc((size_t)E0 * 4);
    int* csr_src  = (int*)alloc((size_t)E0 * 4);
    int* start    = (int*)alloc((N_GRAPHS + 1) * 4);
    int* bsum     = (int*)alloc(SCAN_B * 4);
    int* dhist    = (int*)alloc(NBUCK * 4);
    int* gcur     = (int*)alloc(NBUCK * 4);
    int* order    = (int*)alloc((size_t)N_NODES * 4);
    float* ASa    = (float*)alloc((size_t)N_NODES * 4);
    float* ADa    = (float*)alloc((size_t)N_NODES * 4);
    float* ASb    = (float*)alloc((size_t)N_NODES * 4);
    float* ADb    = (float*)alloc((size_t)N_NODES * 4);
    float* wfold  = (float*)alloc(6 * 128 * 4);
    _Float16* Ha  = (_Float16*)alloc((size_t)N_NODES * HID * 2);
    _Float16* Hb  = (_Float16*)alloc((size_t)N_NODES * HID * 2);
    _Float16* Wh[3];
    for (int l = 0; l < 3; ++l) Wh[l] = (_Float16*)alloc(16384 * 2);

    int nblk = (E0 + 255) / 256;
    hipMemsetAsync(counts, 0, (size_t)N_NODES * 4, stream);
    count_prep<<<nblk + 30, 256, 0, stream>>>(edst, E0, nblk, counts, epos, start, dhist, gcur,
                                              W[0], W[1], W[2], avs[0], avd[0], avs[1], avd[1],
                                              avs[2], avd[2], Wh[0], Wh[1], Wh[2], wfold);
    block_reduce<<<SCAN_B, 256, 0, stream>>>(counts, bsum);
    block_scan<<<SCAN_B, 256, 0, stream>>>(counts, bsum, batch, offs, start, dhist);
    scatter_kernel<<<nblk, 256, 0, stream>>>(esrc, edst, E0, epos, csr_src, (float*)d_out,
                                             offs, dhist, gcur, order);

    // layer 1 GEMM from input x
    gemm_mfma<<<(N_NODES + 63) / 64, 256, 0, stream>>>(x, Wh[0], wfold, wfold + 128,
                                                       Ha, ASa, ADa);
    // layer 1 aggregate + fused layer-2 GEMM/alphas
    aggregate_kernel<<<N_NODES / 16, 256, 0, stream>>>(Ha, ASa, ADa, offs, csr_src, order,
                                                       bb[0], Wh[1], wfold + 2 * 128,
                                                       Hb, ASb, ADb, nullptr, nullptr, nullptr);
    // layer 2 aggregate + fused layer-3 GEMM/alphas
    aggregate_kernel<<<N_NODES / 16, 256, 0, stream>>>(Hb, ASb, ADb, offs, csr_src, order,
                                                       bb[1], Wh[2], wfold + 4 * 128,
                                                       Ha, ASa, ADa, nullptr, nullptr, nullptr);
    // layer 3 aggregate + fused mean-pool into d_out (zeroed in scatter_kernel)
    aggregate_kernel<<<N_NODES / 16, 256, 0, stream>>>(Ha, ASa, ADa, offs, csr_src, order,
                                                       bb[2], nullptr, nullptr,
                                                       nullptr, nullptr, nullptr,
                                                       batch, start, (float*)d_out);
}

// Round 9
// 258.556 us; speedup vs baseline: 1.7430x; 1.7430x over previous
//
#include <hip/hip_runtime.h>
#include <math.h>

#define N_NODES 50000
#define N_GRAPHS 64
#define HID 128
#define SCAN_B 196   // ceil(50000/256)
#define NODE_BLKS 196
#define NBUCK 128
#define AP 132       // padded LDS row stride (halfs) for epilogue A-tile

typedef _Float16 half8 __attribute__((ext_vector_type(8)));
typedef float f32x4 __attribute__((ext_vector_type(4)));
typedef int i32x4 __attribute__((ext_vector_type(4)));

__device__ __forceinline__ float lrelu(float e) { return e > 0.f ? e : 0.2f * e; }
__device__ __forceinline__ float elu_fast(float o) { return o > 0.f ? o : __expf(o) - 1.f; }

// acc += f16(lo/hi half of h2) * c, product+accumulate in f32 — one VALU op
__device__ __forceinline__ void fmix_lo(float& a, int h2, float c) {
    asm("v_fma_mix_f32 %0, %1, %2, %0 op_sel_hi:[1,0,0]" : "+v"(a) : "v"(h2), "v"(c));
}
__device__ __forceinline__ void fmix_hi(float& a, int h2, float c) {
    asm("v_fma_mix_f32 %0, %1, %2, %0 op_sel:[1,0,0] op_sel_hi:[1,0,0]" : "+v"(a) : "v"(h2), "v"(c));
}

// ---------------- CSR count (+ per-edge rank epos) + fused weight prep ----------------
__global__ void count_prep(const int* __restrict__ dst, int n_e, int nblk,
                           int* __restrict__ counts, int* __restrict__ epos,
                           int* __restrict__ start,
                           int* __restrict__ dhist, int* __restrict__ gcur,
                           const float* __restrict__ W0, const float* __restrict__ W1,
                           const float* __restrict__ W2,
                           const float* __restrict__ as0, const float* __restrict__ ad0,
                           const float* __restrict__ as1, const float* __restrict__ ad1,
                           const float* __restrict__ as2, const float* __restrict__ ad2,
                           _Float16* __restrict__ Wh0, _Float16* __restrict__ Wh1,
                           _Float16* __restrict__ Wh2,
                           float* __restrict__ wfold) {
    int blk = blockIdx.x;
    if (blk < nblk) {
        if (blk == 0) {
            if (threadIdx.x <= N_GRAPHS) start[threadIdx.x] = -1;
            if (threadIdx.x < NBUCK) { dhist[threadIdx.x] = 0; gcur[threadIdx.x] = 0; }
        }
        int e = blk * 256 + threadIdx.x;
        if (e < n_e) epos[e] = atomicAdd(&counts[dst[e]], 1);  // rank within dst segment
        return;
    }
    int b = blk - nblk;  // 0..29
    if (b < 24) {
        int layer = b >> 3;
        const float* W = layer == 0 ? W0 : (layer == 1 ? W1 : W2);
        _Float16* Wh = layer == 0 ? Wh0 : (layer == 1 ? Wh1 : Wh2);
        int t = (b & 7) * 256 + threadIdx.x;
        int lane = t & 63;
        int nt = (t >> 6) & 7;
        int kt = t >> 9;
        int n = nt * 16 + (lane & 15);
        int kbase = kt * 32 + (lane >> 4) * 8;
#pragma unroll
        for (int j = 0; j < 8; ++j) {
            float w = W[(size_t)(kbase + j) * 128 + n];
            Wh[(size_t)t * 8 + j] = (_Float16)w;
        }
    } else {
        int idx = b - 24;  // 0..5: layer*2 + which
        int layer = idx >> 1, which = idx & 1;
        const float* W = layer == 0 ? W0 : (layer == 1 ? W1 : W2);
        const float* a = which == 0 ? (layer == 0 ? as0 : (layer == 1 ? as1 : as2))
                                    : (layer == 0 ? ad0 : (layer == 1 ? ad1 : ad2));
        int k = threadIdx.x;
        if (k < 128) {
            float s = 0.f;
            for (int j = 0; j < 128; ++j) s = fmaf(W[k * 128 + j], a[j], s);
            wfold[idx * 128 + k] = s;
        }
    }
}

__global__ __launch_bounds__(256) void block_reduce(const int* __restrict__ counts,
                                                    int* __restrict__ bsum) {
    __shared__ int red[256];
    int t = threadIdx.x;
    int i = blockIdx.x * 256 + t;
    red[t] = (i < N_NODES) ? counts[i] : 0;
    __syncthreads();
#pragma unroll
    for (int off = 128; off; off >>= 1) {
        if (t < off) red[t] += red[t + off];
        __syncthreads();
    }
    if (t == 0) bsum[blockIdx.x] = red[0];
}

// fused: per-block redundant scan of bsum + local scan + boundary detection + degree histogram
__global__ __launch_bounds__(256) void block_scan(const int* __restrict__ counts,
                                                  const int* __restrict__ bsum,
                                                  const int* __restrict__ batch,
                                                  int* __restrict__ offs,
                                                  int* __restrict__ start,
                                                  int* __restrict__ dhist) {
    __shared__ int sb[256];
    __shared__ int sh[256];
    __shared__ int lh[NBUCK];
    int t = threadIdx.x;
    if (t < NBUCK) lh[t] = 0;
    int v = (t < SCAN_B) ? bsum[t] : 0;
    sb[t] = v;
    __syncthreads();
#pragma unroll
    for (int off = 1; off < 256; off <<= 1) {
        int u = (t >= off) ? sb[t - off] : 0;
        __syncthreads();
        sb[t] += u;
        __syncthreads();
    }
    int bpre = (blockIdx.x == 0) ? 0 : sb[blockIdx.x - 1];
    if (blockIdx.x == 0 && t == SCAN_B - 1) offs[N_NODES] = sb[t];

    int i = blockIdx.x * 256 + t;
    int c = (i < N_NODES) ? counts[i] : 0;
    sh[t] = c;
    __syncthreads();
#pragma unroll
    for (int off = 1; off < 256; off <<= 1) {
        int u = (t >= off) ? sh[t - off] : 0;
        __syncthreads();
        sh[t] += u;
        __syncthreads();
    }
    if (i < N_NODES) {
        int e = bpre + sh[t] - c;
        offs[i] = e;
        int b = batch[i];
        if (i == 0) start[b] = 0;
        else if (batch[i - 1] != b) start[b] = i;
        atomicAdd(&lh[c < NBUCK - 1 ? c : NBUCK - 1], 1);
    }
    __syncthreads();
    if (t < NBUCK) {
        int n = lh[t];
        if (n) atomicAdd(&dhist[t], n);
    }
}

// edge scatter (ATOMIC-FREE via epos) + d_out zeroing + degree-bucket placement
__global__ __launch_bounds__(256) void scatter_kernel(const int* __restrict__ src,
                                                      const int* __restrict__ dst, int n_e,
                                                      const int* __restrict__ epos,
                                                      int* __restrict__ csr_src,
                                                      float* __restrict__ outz,
                                                      const int* __restrict__ offs,
                                                      const int* __restrict__ dhist,
                                                      int* __restrict__ gcur,
                                                      int* __restrict__ order) {
    int gid = blockIdx.x * 256 + threadIdx.x;
    if (gid < N_GRAPHS * HID) outz[gid] = 0.f;
    if (gid < n_e) {
        int d = dst[gid];
        csr_src[offs[d] + epos[gid]] = src[gid];
    }
    if (blockIdx.x >= NODE_BLKS) return;

    // two-level counting placement: block-local hist -> one global atomic per bucket
    __shared__ int lh[NBUCK], sc[NBUCK], lbase[NBUCK];
    int t = threadIdx.x;
    if (t < NBUCK) lh[t] = 0;
    __syncthreads();
    int b = -1, lpos = 0;
    if (gid < N_NODES) {
        int deg = offs[gid + 1] - offs[gid];
        b = deg < NBUCK - 1 ? deg : NBUCK - 1;
        lpos = atomicAdd(&lh[b], 1);
    }
    __syncthreads();
    if (t < NBUCK) sc[t] = dhist[t];
    __syncthreads();
    for (int off = 1; off < NBUCK; off <<= 1) {
        int u = (t < NBUCK && t >= off) ? sc[t - off] : 0;
        __syncthreads();
        if (t < NBUCK) sc[t] += u;
        __syncthreads();
    }
    if (t < NBUCK) {
        int excl = t ? sc[t - 1] : 0;
        int cnt = lh[t];
        int bb = cnt ? atomicAdd(&gcur[t], cnt) : 0;
        lbase[t] = excl + bb;
    }
    __syncthreads();
    if (gid < N_NODES) order[lbase[b] + lpos] = gid;
}

// ---------------- MFMA GEMM (layer 1): H16 = fp16(X)@fp16(W); exact fp32 alphas ----------------
__global__ __launch_bounds__(256) void gemm_mfma(const float* __restrict__ X,
                                                 const _Float16* __restrict__ Wh,
                                                 const float* __restrict__ wsv,
                                                 const float* __restrict__ wdv,
                                                 _Float16* __restrict__ H16,
                                                 float* __restrict__ AS,
                                                 float* __restrict__ AD) {
    __shared__ float wsL[128], wdL[128];
    int t = threadIdx.x;
    if (t < 128) wsL[t] = wsv[t];
    else if (t < 256) wdL[t - 128] = wdv[t - 128];
    __syncthreads();

    int wave = t >> 6, lane = t & 63;
    int m15 = lane & 15, quad = lane >> 4;
    int rowbase = blockIdx.x * 64 + wave * 16;
    int arow = rowbase + m15;
    bool arow_ok = arow < N_NODES;

    f32x4 acc[8];
#pragma unroll
    for (int nt = 0; nt < 8; ++nt) acc[nt] = (f32x4){0.f, 0.f, 0.f, 0.f};
    float as_p = 0.f, ad_p = 0.f;

    const float* xrow = X + (size_t)arow * 128 + quad * 8;
#pragma unroll
    for (int kt = 0; kt < 4; ++kt) {
        f32x4 a0 = (f32x4){0.f, 0.f, 0.f, 0.f};
        f32x4 a1 = (f32x4){0.f, 0.f, 0.f, 0.f};
        if (arow_ok) {
            a0 = *(const f32x4*)(xrow + kt * 32);
            a1 = *(const f32x4*)(xrow + kt * 32 + 4);
        }
        int kb = kt * 32 + quad * 8;
        half8 ah;
#pragma unroll
        for (int j = 0; j < 4; ++j) {
            as_p = fmaf(a0[j], wsL[kb + j], as_p);
            ad_p = fmaf(a0[j], wdL[kb + j], ad_p);
            as_p = fmaf(a1[j], wsL[kb + 4 + j], as_p);
            ad_p = fmaf(a1[j], wdL[kb + 4 + j], ad_p);
            ah[j] = (_Float16)a0[j];
            ah[4 + j] = (_Float16)a1[j];
        }
#pragma unroll
        for (int nt = 0; nt < 8; ++nt) {
            size_t fidx = ((size_t)((kt * 8 + nt) * 64 + lane)) * 8;
            half8 bh = *(const half8*)(Wh + fidx);
            acc[nt] = __builtin_amdgcn_mfma_f32_16x16x32_f16(ah, bh, acc[nt], 0, 0, 0);
        }
    }

#pragma unroll
    for (int nt = 0; nt < 8; ++nt) {
        int c = nt * 16 + m15;
#pragma unroll
        for (int reg = 0; reg < 4; ++reg) {
            int gr = rowbase + quad * 4 + reg;
            if (gr < N_NODES) H16[(size_t)gr * 128 + c] = (_Float16)acc[nt][reg];
        }
    }
    as_p += __shfl_xor(as_p, 16);
    ad_p += __shfl_xor(ad_p, 16);
    as_p += __shfl_xor(as_p, 32);
    ad_p += __shfl_xor(ad_p, 32);
    if (quad == 0 && arow_ok) { AS[arow] = as_p; AD[arow] = ad_p; }
}

// ---------------- fused softmax + fp16 gather + NEXT-LAYER GEMM epilogue ----------------
// Byte-identical to the R4 champion version (no pool fusion — see R8 post-mortem).
__global__ __launch_bounds__(256) void aggregate_kernel(const _Float16* __restrict__ H16,
                                                        const float* __restrict__ AS,
                                                        const float* __restrict__ AD,
                                                        const int* __restrict__ offs,
                                                        const int* __restrict__ csr_src,
                                                        const int* __restrict__ order,
                                                        const float* __restrict__ bias,
                                                        const _Float16* __restrict__ Whn,
                                                        const float* __restrict__ wfn,
                                                        _Float16* __restrict__ Hn,
                                                        float* __restrict__ ASn,
                                                        float* __restrict__ ADn,
                                                        float* __restrict__ OUT) {
    __shared__ int2 sh_sp[16][64];
    __shared__ _Float16 aW[16][AP];
    __shared__ int nds[16];
    int tid = threadIdx.x;
    int quad = tid >> 4;
    int l16 = tid & 15;
    int node = order[blockIdx.x * 16 + quad];

    int beg = offs[node];
    int deg = offs[node + 1] - beg;
    float ad = AD[node];
    float eself = lrelu(AS[node] + ad);
    const i32x4* H4 = (const i32x4*)H16;
    i32x4 hsv = H4[(size_t)node * 16 + l16];
    bool fast = deg <= 64;

    float m, ssum = 0.f, ps;
    if (fast) {
        float mym = -INFINITY;
        for (int i = l16; i < deg; i += 16) {
            int sv = csr_src[beg + i];
            float e = lrelu(AS[sv] + ad);
            sh_sp[quad][i] = make_int2(sv, __float_as_int(e));
            mym = fmaxf(mym, e);
        }
#pragma unroll
        for (int off = 8; off; off >>= 1) mym = fmaxf(mym, __shfl_xor(mym, off, 16));
        m = fmaxf(mym, eself);
        ps = __expf(eself - m);
        for (int i = l16; i < deg; i += 16) {
            int2 sp = sh_sp[quad][i];
            float p = __expf(__int_as_float(sp.y) - m);
            sh_sp[quad][i] = make_int2(sp.x, __float_as_int(p));
            ssum += p;
        }
    } else {
        float mym = -INFINITY;
        for (int i = beg + l16; i < beg + deg; i += 16)
            mym = fmaxf(mym, lrelu(AS[csr_src[i]] + ad));
#pragma unroll
        for (int off = 8; off; off >>= 1) mym = fmaxf(mym, __shfl_xor(mym, off, 16));
        m = fmaxf(mym, eself);
        ps = __expf(eself - m);
        for (int i = beg + l16; i < beg + deg; i += 16)
            ssum += __expf(lrelu(AS[csr_src[i]] + ad) - m);
    }

    float accA[8] = {0.f, 0.f, 0.f, 0.f, 0.f, 0.f, 0.f, 0.f};
    float accB[8] = {0.f, 0.f, 0.f, 0.f, 0.f, 0.f, 0.f, 0.f};

    if (fast) {
        int k = 0;
        for (; k + 3 < deg; k += 4) {
            int2 sp0 = sh_sp[quad][k];
            int2 sp1 = sh_sp[quad][k + 1];
            int2 sp2 = sh_sp[quad][k + 2];
            int2 sp3 = sh_sp[quad][k + 3];
            i32x4 h0 = H4[(size_t)sp0.x * 16 + l16];
            i32x4 h1 = H4[(size_t)sp1.x * 16 + l16];
            i32x4 h2 = H4[(size_t)sp2.x * 16 + l16];
            i32x4 h3 = H4[(size_t)sp3.x * 16 + l16];
            float c0 = __int_as_float(sp0.y), c1 = __int_as_float(sp1.y);
            float c2 = __int_as_float(sp2.y), c3 = __int_as_float(sp3.y);
#pragma unroll
            for (int j = 0; j < 4; ++j) {
                fmix_lo(accA[2 * j], h0[j], c0);
                fmix_hi(accA[2 * j + 1], h0[j], c0);
                fmix_lo(accB[2 * j], h1[j], c1);
                fmix_hi(accB[2 * j + 1], h1[j], c1);
            }
#pragma unroll
            for (int j = 0; j < 4; ++j) {
                fmix_lo(accA[2 * j], h2[j], c2);
                fmix_hi(accA[2 * j + 1], h2[j], c2);
                fmix_lo(accB[2 * j], h3[j], c3);
                fmix_hi(accB[2 * j + 1], h3[j], c3);
            }
        }
        for (; k < deg; ++k) {
            int2 sp0 = sh_sp[quad][k];
            float c0 = __int_as_float(sp0.y);
            i32x4 h0 = H4[(size_t)sp0.x * 16 + l16];
#pragma unroll
            for (int j = 0; j < 4; ++j) {
                fmix_lo(accA[2 * j], h0[j], c0);
                fmix_hi(accA[2 * j + 1], h0[j], c0);
            }
        }
    } else {
        for (int k = 0; k < deg; ++k) {
            int s = csr_src[beg + k];
            float c = __expf(lrelu(AS[s] + ad) - m);
            i32x4 h0 = H4[(size_t)s * 16 + l16];
#pragma unroll
            for (int j = 0; j < 4; ++j) {
                fmix_lo(accA[2 * j], h0[j], c);
                fmix_hi(accA[2 * j + 1], h0[j], c);
            }
        }
    }

#pragma unroll
    for (int j = 0; j < 4; ++j) {
        fmix_lo(accA[2 * j], hsv[j], ps);
        fmix_hi(accA[2 * j + 1], hsv[j], ps);
    }
#pragma unroll
    for (int off = 8; off; off >>= 1) ssum += __shfl_xor(ssum, off, 16);
    float inv = __builtin_amdgcn_rcpf(ssum + ps + 1e-16f);

    int c0i = l16 * 8;
    f32x4 b0 = ((const f32x4*)bias)[l16 * 2];
    f32x4 b1 = ((const f32x4*)bias)[l16 * 2 + 1];
    f32x4 o0, o1;
    o0.x = elu_fast(fmaf(accA[0] + accB[0], inv, b0.x));
    o0.y = elu_fast(fmaf(accA[1] + accB[1], inv, b0.y));
    o0.z = elu_fast(fmaf(accA[2] + accB[2], inv, b0.z));
    o0.w = elu_fast(fmaf(accA[3] + accB[3], inv, b0.w));
    o1.x = elu_fast(fmaf(accA[4] + accB[4], inv, b1.x));
    o1.y = elu_fast(fmaf(accA[5] + accB[5], inv, b1.y));
    o1.z = elu_fast(fmaf(accA[6] + accB[6], inv, b1.z));
    o1.w = elu_fast(fmaf(accA[7] + accB[7], inv, b1.w));
    if (OUT) {
        ((f32x4*)OUT)[(size_t)node * 32 + l16 * 2] = o0;
        ((f32x4*)OUT)[(size_t)node * 32 + l16 * 2 + 1] = o1;
    }

    if (Whn) {
        const float* wsn = wfn;
        const float* wdn = wfn + 128;
        float asn = o0.x * wsn[c0i] + o0.y * wsn[c0i + 1] + o0.z * wsn[c0i + 2] +
                    o0.w * wsn[c0i + 3] + o1.x * wsn[c0i + 4] + o1.y * wsn[c0i + 5] +
                    o1.z * wsn[c0i + 6] + o1.w * wsn[c0i + 7];
        float adn = o0.x * wdn[c0i] + o0.y * wdn[c0i + 1] + o0.z * wdn[c0i + 2] +
                    o0.w * wdn[c0i + 3] + o1.x * wdn[c0i + 4] + o1.y * wdn[c0i + 5] +
                    o1.z * wdn[c0i + 6] + o1.w * wdn[c0i + 7];
#pragma unroll
        for (int off = 8; off; off >>= 1) {
            asn += __shfl_xor(asn, off, 16);
            adn += __shfl_xor(adn, off, 16);
        }
        if (l16 == 0) {
            ASn[node] = asn;
            ADn[node] = adn;
            nds[quad] = node;
        }
        half8 hh;
        hh[0] = (_Float16)o0.x; hh[1] = (_Float16)o0.y;
        hh[2] = (_Float16)o0.z; hh[3] = (_Float16)o0.w;
        hh[4] = (_Float16)o1.x; hh[5] = (_Float16)o1.y;
        hh[6] = (_Float16)o1.z; hh[7] = (_Float16)o1.w;
        *(half8*)&aW[quad][c0i] = hh;
        __syncthreads();

        int wv = tid >> 6, lane = tid & 63;
        int m15 = lane & 15, eq = lane >> 4;
        f32x4 acc0 = (f32x4){0.f, 0.f, 0.f, 0.f};
        f32x4 acc1 = (f32x4){0.f, 0.f, 0.f, 0.f};
#pragma unroll
        for (int kt = 0; kt < 4; ++kt) {
            half8 ah = *(const half8*)&aW[m15][kt * 32 + eq * 8];
            half8 bh0 = *(const half8*)(Whn + ((size_t)((kt * 8 + wv * 2) * 64 + lane)) * 8);
            half8 bh1 = *(const half8*)(Whn + ((size_t)((kt * 8 + wv * 2 + 1) * 64 + lane)) * 8);
            acc0 = __builtin_amdgcn_mfma_f32_16x16x32_f16(ah, bh0, acc0, 0, 0, 0);
            acc1 = __builtin_amdgcn_mfma_f32_16x16x32_f16(ah, bh1, acc1, 0, 0, 0);
        }
#pragma unroll
        for (int reg = 0; reg < 4; ++reg) {
            int nid = nds[eq * 4 + reg];
            Hn[(size_t)nid * 128 + wv * 32 + m15] = (_Float16)acc0[reg];
            Hn[(size_t)nid * 128 + wv * 32 + 16 + m15] = (_Float16)acc1[reg];
        }
    }
}

// ---------------- single-dispatch pool: pre-divided atomic accumulate ----------------
__device__ __forceinline__ int estart(const int* __restrict__ start, int g) {
    for (; g < N_GRAPHS; ++g) {
        int v = start[g];
        if (v >= 0) return v;
    }
    return N_NODES;
}

__global__ __launch_bounds__(128) void pool_kernel(const float* __restrict__ F,
                                                   const int* __restrict__ start,
                                                   float* __restrict__ out) {
    int b = blockIdx.x;
    int g = b >> 4, sub = b & 15;
    int c = threadIdx.x;
    int s0 = estart(start, g), e0 = estart(start, g + 1);
    float acc = 0.f;
    for (int i = s0 + sub; i < e0; i += 16) acc += F[(size_t)i * 128 + c];
    int cnt = e0 - s0;
    float r = 1.f / (float)(cnt > 1 ? cnt : 1);
    atomicAdd(&out[(size_t)g * 128 + c], acc * r);
}

extern "C" void kernel_launch(void* const* d_in, const int* in_sizes, int n_in,
                              void* d_out, int out_size, void* d_ws, size_t ws_size,
                              hipStream_t stream) {
    const float* x = (const float*)d_in[0];
    const int* edge_index = (const int*)d_in[1];
    const int* batch = (const int*)d_in[2];
    const float* W[3]   = {(const float*)d_in[3], (const float*)d_in[7], (const float*)d_in[11]};
    const float* avs[3] = {(const float*)d_in[4], (const float*)d_in[8], (const float*)d_in[12]};
    const float* avd[3] = {(const float*)d_in[5], (const float*)d_in[9], (const float*)d_in[13]};
    const float* bb[3]  = {(const float*)d_in[6], (const float*)d_in[10], (const float*)d_in[14]};
    int E0 = in_sizes[1] / 2;
    const int* esrc = edge_index;
    const int* edst = edge_index + E0;

    char* p = (char*)d_ws;
    auto alloc = [&](size_t bytes) -> void* {
        void* q = (void*)p;
        p += (bytes + 255) & ~(size_t)255;
        return q;
    };
    int* counts   = (int*)alloc((size_t)N_NODES * 4);
    int* offs     = (int*)alloc((size_t)(N_NODES + 1) * 4);
    int* epos     = (int*)alloc((size_t)E0 * 4);
    int* csr_src  = (int*)alloc((size_t)E0 * 4);
    int* start    = (int*)alloc((N_GRAPHS + 1) * 4);
    int* bsum     = (int*)alloc(SCAN_B * 4);
    int* dhist    = (int*)alloc(NBUCK * 4);
    int* gcur     = (int*)alloc(NBUCK * 4);
    int* order    = (int*)alloc((size_t)N_NODES * 4);
    float* ASa    = (float*)alloc((size_t)N_NODES * 4);
    float* ADa    = (float*)alloc((size_t)N_NODES * 4);
    float* ASb    = (float*)alloc((size_t)N_NODES * 4);
    float* ADb    = (float*)alloc((size_t)N_NODES * 4);
    float* wfold  = (float*)alloc(6 * 128 * 4);
    _Float16* Ha  = (_Float16*)alloc((size_t)N_NODES * HID * 2);
    _Float16* Hb  = (_Float16*)alloc((size_t)N_NODES * HID * 2);
    float* FA     = (float*)alloc((size_t)N_NODES * HID * 4);
    _Float16* Wh[3];
    for (int l = 0; l < 3; ++l) Wh[l] = (_Float16*)alloc(16384 * 2);

    int nblk = (E0 + 255) / 256;
    hipMemsetAsync(counts, 0, (size_t)N_NODES * 4, stream);
    count_prep<<<nblk + 30, 256, 0, stream>>>(edst, E0, nblk, counts, epos, start, dhist, gcur,
                                              W[0], W[1], W[2], avs[0], avd[0], avs[1], avd[1],
                                              avs[2], avd[2], Wh[0], Wh[1], Wh[2], wfold);
    block_reduce<<<SCAN_B, 256, 0, stream>>>(counts, bsum);
    block_scan<<<SCAN_B, 256, 0, stream>>>(counts, bsum, batch, offs, start, dhist);
    scatter_kernel<<<nblk, 256, 0, stream>>>(esrc, edst, E0, epos, csr_src, (float*)d_out,
                                             offs, dhist, gcur, order);

    // layer 1 GEMM from input x
    gemm_mfma<<<(N_NODES + 63) / 64, 256, 0, stream>>>(x, Wh[0], wfold, wfold + 128,
                                                       Ha, ASa, ADa);
    // layer 1 aggregate + fused layer-2 GEMM/alphas
    aggregate_kernel<<<N_NODES / 16, 256, 0, stream>>>(Ha, ASa, ADa, offs, csr_src, order,
                                                       bb[0], Wh[1], wfold + 2 * 128,
                                                       Hb, ASb, ADb, nullptr);
    // layer 2 aggregate + fused layer-3 GEMM/alphas
    aggregate_kernel<<<N_NODES / 16, 256, 0, stream>>>(Hb, ASb, ADb, offs, csr_src, order,
                                                       bb[1], Wh[2], wfold + 4 * 128,
                                                       Ha, ASa, ADa, nullptr);
    // layer 3 aggregate -> fp32 FA for pool
    aggregate_kernel<<<N_NODES / 16, 256, 0, stream>>>(Ha, ASa, ADa, offs, csr_src, order,
                                                       bb[2], nullptr, nullptr,
                                                       nullptr, nullptr, nullptr, FA);

    // single-dispatch pool (d_out zeroed in scatter_kernel)
    pool_kernel<<<N_GRAPHS * 16, 128, 0, stream>>>(FA, start, (float*)d_out);
}